// Round 6
// baseline (94.783 us; speedup 1.0000x reference)
//
#include <hip/hip_runtime.h>
#include <math.h>

// Problem constants
#define BB 16
#define HH 128
#define WW 128
#define RR 4      // reward_dim
#define AA 8      // action_channels
#define II 5      // R+1
#define CC 45     // I*K*K
#define NPIX (BB*HH*WW)
#define LOG2E 1.4426950408889634f

typedef __attribute__((ext_vector_type(8))) short v8s;      // 8 x bf16 (MFMA A/B frag)
typedef __attribute__((ext_vector_type(4))) float v4f;      // MFMA C/D frag
typedef __attribute__((ext_vector_type(2))) float v2f;      // packed f32 pair
typedef __attribute__((ext_vector_type(4))) unsigned short v4u16;

// Repacked bf16 weight fragments, ELEMENT index (shared by both kernels):
//   e = (o*6 + mt*2 + ks)*512 + lane*8 + j      (lane-linear: wave reads 1KB seq)
// Lane l holds A[ch = mt*16 + (l&15)][k = ks*32 + (l>>4)*8 + j], pre-scaled by
// log2(e) so v_exp_f32 (2^x) gives e^logit directly.  M pad 45->48 (zero rows),
// K pad 45->64 (zeros).
__device__ __align__(16) unsigned short g_wbf[AA * 3072];   // 24576 elements

__device__ __forceinline__ unsigned short f2bf(float f) {
    union { float f; unsigned int u; } v; v.f = f;
    unsigned int r = v.u + 0x7fffu + ((v.u >> 16) & 1u);   // round-to-nearest-even
    return (unsigned short)(r >> 16);
}

__global__ __launch_bounds__(256) void repack_kernel(const float* __restrict__ w) {
    const int e = blockIdx.x * 256 + threadIdx.x;
    if (e >= AA * 3072) return;
    const int o    = e / 3072;
    const int rem  = e - o * 3072;
    const int mtks = rem >> 9;            // 0..5
    const int l    = (rem >> 3) & 63;     // lane
    const int j    = rem & 7;
    const int mt   = mtks >> 1;
    const int ks   = mtks & 1;
    const int ch   = mt * 16 + (l & 15);          // 0..47
    const int k    = ks * 32 + (l >> 4) * 8 + j;  // 0..63
    float v = 0.0f;
    if (ch < CC && k < CC) v = w[(o * CC + ch) * CC + k] * LOG2E;
    g_wbf[e] = f2bf(v);
}

// ---- main fused kernel ----
// 2048 blocks x 128 threads (2 waves). Block = one image row (b,h); wave wv owns
// 64 consecutive pixels (w0 = wv*64), i.e. 4 tiles of 16. LDS is wave-private
// (no __syncthreads): 64 rows x 72 bf16 per wave (stride 72 => 16B-aligned frags).
__global__ __launch_bounds__(128, 4) void vi_mfma(
    const float* __restrict__ values,   // [B,H,W]
    const float* __restrict__ rewards,  // [B,R,H,W]
    float* __restrict__ out)            // [B,H,W]
{
    __shared__ __align__(16) unsigned short lds[2 * 64 * 72]; // 18432 B
    const int lane = threadIdx.x & 63;
    const int wv   = threadIdx.x >> 6;
    const int c    = lane & 15;        // pixel within tile / D col
    const int g    = lane >> 4;        // lane group
    const int row  = blockIdx.x;       // b*128 + h
    const int b    = row >> 7;
    const int h    = row & 127;
    const int w0   = wv * 64;
    const int P0   = row * 128 + w0;
    const int wbase = wv * (64 * 72);

    // zero-fill this wave's region (covers K pad 45..71; staging overwrites <45)
    {
        v8s z = {0,0,0,0,0,0,0,0};
        #pragma unroll
        for (int qq = 0; qq < 9; ++qq)
            *(v8s*)(&lds[wbase + lane * 72 + qq * 8]) = z;
    }

    // stage patches: lane (c,g) writes pixel c of each tile, elems j = g*12+tt
    #pragma unroll
    for (int t = 0; t < 4; ++t) {
        const int pw = w0 + t * 16 + c;
        #pragma unroll
        for (int tt = 0; tt < 12; ++tt) {
            const int j = g * 12 + tt;
            if (j < CC) {                       // false only for g==3, tt>=9
                const int i  = j / 9;
                const int r9 = j - i * 9;
                const int k1 = r9 / 3;
                const int k2 = r9 - k1 * 3;
                const int y = h + k1 - 1;
                const int x = pw + k2 - 1;
                float f = 0.0f;
                if (y >= 0 && y < HH && x >= 0 && x < WW)
                    f = (i < RR) ? rewards[((b * RR + i) * HH + y) * WW + x]
                                 : values[(b * HH + y) * WW + x];
                lds[wbase + (t * 16 + c) * 72 + j] = f2bf(f);
            }
        }
    }

    // B fragments: lane (c,g) holds patch[pix=c][k = ks*32 + g*8 + 0..7]
    v8s Bf[4][2];
    #pragma unroll
    for (int t = 0; t < 4; ++t)
        #pragma unroll
        for (int ks = 0; ks < 2; ++ks)
            Bf[t][ks] = *(const v8s*)(&lds[wbase + (t * 16 + c) * 72 + ks * 32 + g * 8]);

    // patch weights for q: o-invariant -> unpack to f32 pairs ONCE (48 VGPR),
    // removing 12 lshl per (o,t) from the hot loop.
    v2f pvf[4][3][2];
    #pragma unroll
    for (int t = 0; t < 4; ++t)
        #pragma unroll
        for (int mt = 0; mt < 3; ++mt) {
            const v4u16 pu = *(const v4u16*)(&lds[wbase + (t * 16 + c) * 72
                                                  + mt * 16 + g * 4]);
            #pragma unroll
            for (int rp = 0; rp < 2; ++rp) {
                pvf[t][mt][rp][0] = __uint_as_float(((unsigned int)pu[2 * rp + 0]) << 16);
                pvf[t][mt][rp][1] = __uint_as_float(((unsigned int)pu[2 * rp + 1]) << 16);
            }
        }

    float best[4] = {-1e30f, -1e30f, -1e30f, -1e30f};
    const unsigned short* wb = g_wbf;

    #pragma unroll 1    // keep I$ small; A-frags reloaded per action (L1/L2-hot)
    for (int o = 0; o < AA; ++o) {
        v8s Af[3][2];
        #pragma unroll
        for (int mt = 0; mt < 3; ++mt)
            #pragma unroll
            for (int ks = 0; ks < 2; ++ks)
                Af[mt][ks] = *(const v8s*)(wb + (o * 6 + mt * 2 + ks) * 512 + lane * 8);
        #pragma unroll
        for (int t = 0; t < 4; ++t) {
            // logits (x log2e): D layout (m89): pix = lane&15, ch = mt*16 + 4*g + reg
            v4f acc[3];
            #pragma unroll
            for (int mt = 0; mt < 3; ++mt) {
                acc[mt] = (v4f){0.f, 0.f, 0.f, 0.f};
                acc[mt] = __builtin_amdgcn_mfma_f32_16x16x32_bf16(Af[mt][0], Bf[t][0], acc[mt], 0, 0, 0);
                acc[mt] = __builtin_amdgcn_mfma_f32_16x16x32_bf16(Af[mt][1], Bf[t][1], acc[mt], 0, 0, 0);
            }
            // softmax: 2^(x*log2e) = e^x; shift-free (logits ~N(0,1)).
            // pad channels 45..47: weight rows exactly 0 -> logit 0 -> 2^0 = 1;
            // summed in, removed as (s - 3) after the reduce (their pv is 0).
            // Packed pairs: ssum += {e0,e1} (v_pk_add), qsum += {e0,e1}*pv (v_pk_fma).
            v2f ssum = {0.f, 0.f}, qsum = {0.f, 0.f};
            #pragma unroll
            for (int mt = 0; mt < 3; ++mt) {
                #pragma unroll
                for (int rp = 0; rp < 2; ++rp) {
                    v2f ep;
                    ep[0] = __builtin_amdgcn_exp2f(acc[mt][2 * rp + 0]);
                    ep[1] = __builtin_amdgcn_exp2f(acc[mt][2 * rp + 1]);
                    ssum += ep;
                    qsum += ep * pvf[t][mt][rp];
                }
            }
            float s = ssum[0] + ssum[1];
            float q = qsum[0] + qsum[1];
            // channels live in lanes {c, c+16, c+32, c+48}: butterfly over g
            s += __shfl_xor(s, 16);  q += __shfl_xor(q, 16);
            s += __shfl_xor(s, 32);  q += __shfl_xor(q, 32);
            best[t] = fmaxf(best[t], q * __builtin_amdgcn_rcpf(s - 3.0f));
        }
    }

    if (g == 0) {
        #pragma unroll
        for (int t = 0; t < 4; ++t)
            out[P0 + t * 16 + c] = best[t];
    }
}

extern "C" void kernel_launch(void* const* d_in, const int* in_sizes, int n_in,
                              void* d_out, int out_size, void* d_ws, size_t ws_size,
                              hipStream_t stream) {
    const float* values  = (const float*)d_in[0];
    const float* rewards = (const float*)d_in[1];
    const float* weight  = (const float*)d_in[2];
    float* out = (float*)d_out;

    repack_kernel<<<96, 256, 0, stream>>>(weight);            // 24576 elems
    vi_mfma<<<2048, 128, 0, stream>>>(values, rewards, out);  // 8 blocks/CU even
}